// Round 1
// 1112.634 us; speedup vs baseline: 1.0551x; 1.0551x over previous
//
#include <hip/hip_runtime.h>
#include <math.h>

#define T_ 32
#define P_ 14
#define H_ 12
#define D_ 64
#define L_ 196
#define DM_ 768
#define S_ 16

typedef __attribute__((ext_vector_type(8))) short short8;
typedef __attribute__((ext_vector_type(8))) unsigned short ushort8;
typedef __attribute__((ext_vector_type(4))) float f32x4;

// Fragment read for mfma_f32_16x16x32_bf16: lane holds row = 16*ib + (lane&15),
// k-cols (lane>>4)*8 + 32*ks .. +7  (16B), XOR-swizzled by row to kill the
// 16-way stride-128B bank conflict (G4).
__device__ __forceinline__ short8 ldfrag(const char* plane, int ib, int ks, int lane) {
    const int row = (ib << 4) + (lane & 15);
    const int c16 = (lane >> 4) + (ks << 2);
    return *(const short8*)(plane + row * 128 + ((c16 ^ (row & 7)) << 4));
}

// ---------------- Kernel A: temporal path, one wg per (b, l) ----------------
// Wave-per-channel: wave w owns channels w*6..w*6+5 with PRIVATE LDS buffers
// -> no __syncthreads in the 24-channel main loop.
// Gram via MFMA bf16 3-term split (hi*hi + hi*lo + lo*hi, fp32 accum) ~= fp32.
__global__ __launch_bounds__(256)
void temporal_kernel(const float* __restrict__ q, const float* __restrict__ k,
                     const float* __restrict__ tw, const float* __restrict__ tbias,
                     const float* __restrict__ lng, const float* __restrict__ lnb,
                     const float* __restrict__ w1, const float* __restrict__ b1,
                     const float* __restrict__ w2, const float* __restrict__ b2,
                     float* __restrict__ affbuf)
{
    const int l = blockIdx.x;   // 0..195
    const int b = blockIdx.y;   // 0..15
    const int tid = threadIdx.x;
    const int lane = tid & 63;
    const int w = tid >> 6;     // wave id 0..3

    // Region A: per-wave bf16 X planes (hi 4KB + lo 4KB) = 32KB. Overlaid by
    //           nls[1024] (LN output) after the channel loop.
    // Region B: per-wave P planes 32x36 f32 (4608B) = 18.4KB. Overlaid by the
    //           per-wave conv-accumulator planes (4KB each) after the loop.
    __shared__ __align__(16) char sm_[32768 + 18432];
    __shared__ float scratch[256];
    __shared__ float h1s[32];
    __shared__ float redv[8];

    char* XHw = sm_ + w * 8192;
    char* XLw = XHw + 4096;
    float* As = (float*)(sm_ + 32768 + w * 4608);   // pitch 36 floats

    const int r = lane >> 1;          // row 0..31 (both staging and conv)
    const int half_ = lane & 1;       // which 32-col half (staging) / 16-col half (conv)
    const int hf4 = half_ << 2;
    const int c0 = half_ << 4;        // conv col base: 0 or 16

    float cc16[16];
    #pragma unroll
    for (int i = 0; i < 16; ++i) cc16[i] = 0.f;

    // prologue: load first channel's 32 floats (row r, half half_)
    float4 fr[8];
    {
        const int ch = w * 6;
        const float* src = (ch < H_) ? q : k;
        const int h = (ch < H_) ? ch : ch - H_;
        const float* rowp = src + (((size_t)(b * T_ + r) * 197 + 1 + l) * DM_) + h * D_ + (half_ << 5);
        #pragma unroll
        for (int u = 0; u < 8; ++u) fr[u] = *(const float4*)(rowp + (u << 2));
    }

    #pragma unroll
    for (int cc = 0; cc < 6; ++cc) {
        const int ch = w * 6 + cc;
        // ---- split f32 -> bf16 hi/lo (RNE both) ----
        ushort8 hv[4], lv[4];
        #pragma unroll
        for (int u4 = 0; u4 < 4; ++u4) {
            float xs[8] = {fr[2*u4].x, fr[2*u4].y, fr[2*u4].z, fr[2*u4].w,
                           fr[2*u4+1].x, fr[2*u4+1].y, fr[2*u4+1].z, fr[2*u4+1].w};
            #pragma unroll
            for (int j = 0; j < 8; ++j) {
                const unsigned u = __float_as_uint(xs[j]);
                const unsigned hb = (u + 0x7fffu + ((u >> 16) & 1u)) & 0xffff0000u;
                const float res = xs[j] - __uint_as_float(hb);
                const unsigned u2 = __float_as_uint(res);
                const unsigned lb = u2 + 0x7fffu + ((u2 >> 16) & 1u);
                hv[u4][j] = (unsigned short)(hb >> 16);
                lv[u4][j] = (unsigned short)(lb >> 16);
            }
        }
        // ---- prefetch next channel's globals under the compute below ----
        if (cc < 5) {
            const int ch2 = ch + 1;
            const float* src = (ch2 < H_) ? q : k;
            const int h = (ch2 < H_) ? ch2 : ch2 - H_;
            const float* rowp = src + (((size_t)(b * T_ + r) * 197 + 1 + l) * DM_) + h * D_ + (half_ << 5);
            #pragma unroll
            for (int u = 0; u < 8; ++u) fr[u] = *(const float4*)(rowp + (u << 2));
        }
        // ---- stage swizzled bf16 planes (wave-private, no barrier) ----
        #pragma unroll
        for (int u4 = 0; u4 < 4; ++u4) {
            const int sw = (((hf4 + u4) ^ (r & 7)) << 4);
            *(ushort8*)(XHw + r * 128 + sw) = hv[u4];
            *(ushort8*)(XLw + r * 128 + sw) = lv[u4];
        }
        __builtin_amdgcn_wave_barrier();
        // ---- gram via MFMA: G = Hi*Hi^T + Hi*Lo^T + Lo*Hi^T (fp32 acc) ----
        f32x4 a00 = {0.f, 0.f, 0.f, 0.f};
        f32x4 a01 = a00, a10 = a00, a11 = a00;
        #pragma unroll
        for (int ks = 0; ks < 2; ++ks) {
            short8 h0 = ldfrag(XHw, 0, ks, lane);
            short8 h1 = ldfrag(XHw, 1, ks, lane);
            short8 g0 = ldfrag(XLw, 0, ks, lane);
            short8 g1 = ldfrag(XLw, 1, ks, lane);
            a00 = __builtin_amdgcn_mfma_f32_16x16x32_bf16(h0, h0, a00, 0, 0, 0);
            a01 = __builtin_amdgcn_mfma_f32_16x16x32_bf16(h0, h1, a01, 0, 0, 0);
            a10 = __builtin_amdgcn_mfma_f32_16x16x32_bf16(h1, h0, a10, 0, 0, 0);
            a11 = __builtin_amdgcn_mfma_f32_16x16x32_bf16(h1, h1, a11, 0, 0, 0);
            a00 = __builtin_amdgcn_mfma_f32_16x16x32_bf16(h0, g0, a00, 0, 0, 0);
            a01 = __builtin_amdgcn_mfma_f32_16x16x32_bf16(h0, g1, a01, 0, 0, 0);
            a10 = __builtin_amdgcn_mfma_f32_16x16x32_bf16(h1, g0, a10, 0, 0, 0);
            a11 = __builtin_amdgcn_mfma_f32_16x16x32_bf16(h1, g1, a11, 0, 0, 0);
            a00 = __builtin_amdgcn_mfma_f32_16x16x32_bf16(g0, h0, a00, 0, 0, 0);
            a01 = __builtin_amdgcn_mfma_f32_16x16x32_bf16(g0, h1, a01, 0, 0, 0);
            a10 = __builtin_amdgcn_mfma_f32_16x16x32_bf16(g1, h0, a10, 0, 0, 0);
            a11 = __builtin_amdgcn_mfma_f32_16x16x32_bf16(g1, h1, a11, 0, 0, 0);
        }
        // ---- row softmax (over k = cols) fully in registers; write P to As --
        // C layout (m89): col = lane&15, row = 4*(lane>>4)+reg (+16 per ib/jb)
        {
            const int col = lane & 15;
            const int rbase = (lane >> 4) << 2;
            #pragma unroll
            for (int ib = 0; ib < 2; ++ib) {
                #pragma unroll
                for (int rg = 0; rg < 4; ++rg) {
                    float gA = (ib ? a10[rg] : a00[rg]) * 0.125f;  // 1/sqrt(64)
                    float gB = (ib ? a11[rg] : a01[rg]) * 0.125f;
                    float m = fmaxf(gA, gB);
                    m = fmaxf(m, __shfl_xor(m, 1, 16));
                    m = fmaxf(m, __shfl_xor(m, 2, 16));
                    m = fmaxf(m, __shfl_xor(m, 4, 16));
                    m = fmaxf(m, __shfl_xor(m, 8, 16));
                    float e0 = __expf(gA - m), e1 = __expf(gB - m);
                    float s = e0 + e1;
                    s += __shfl_xor(s, 1, 16);
                    s += __shfl_xor(s, 2, 16);
                    s += __shfl_xor(s, 4, 16);
                    s += __shfl_xor(s, 8, 16);
                    const float rinv = 1.f / s;
                    const int row = (ib << 4) + rbase + rg;
                    As[row * 36 + col] = e0 * rinv;
                    As[row * 36 + col + 16] = e1 * rinv;
                }
            }
        }
        __builtin_amdgcn_wave_barrier();
        // ---- 3x3 conv accumulate (SAME pad, correlation), lane = (r, c0) ----
        {
            float wcv[9];
            #pragma unroll
            for (int u = 0; u < 9; ++u) wcv[u] = tw[ch * 9 + u];
            #pragma unroll
            for (int dr = 0; dr < 3; ++dr) {
                const int rr = r + dr - 1;
                if ((unsigned)rr < 32u) {
                    const float* rp = As + rr * 36;
                    float vb[18];
                    vb[0] = half_ ? rp[15] : 0.f;
                    float4 m0 = *(const float4*)&rp[c0];
                    float4 m1 = *(const float4*)&rp[c0 + 4];
                    float4 m2 = *(const float4*)&rp[c0 + 8];
                    float4 m3 = *(const float4*)&rp[c0 + 12];
                    vb[1] = m0.x;  vb[2] = m0.y;  vb[3] = m0.z;  vb[4] = m0.w;
                    vb[5] = m1.x;  vb[6] = m1.y;  vb[7] = m1.z;  vb[8] = m1.w;
                    vb[9] = m2.x;  vb[10] = m2.y; vb[11] = m2.z; vb[12] = m2.w;
                    vb[13] = m3.x; vb[14] = m3.y; vb[15] = m3.z; vb[16] = m3.w;
                    vb[17] = half_ ? 0.f : rp[16];
                    const float w0v = wcv[dr * 3], w1v = wcv[dr * 3 + 1], w2v = wcv[dr * 3 + 2];
                    #pragma unroll
                    for (int c = 0; c < 16; ++c)
                        cc16[c] += w0v * vb[c] + w1v * vb[c + 1] + w2v * vb[c + 2];
                }
            }
        }
        __builtin_amdgcn_wave_barrier();
    }
    // ---- dump per-wave conv plane (overlay onto own As plane), then join ----
    {
        float* cpw = As;
        #pragma unroll
        for (int u = 0; u < 4; ++u) {
            float4 o;
            o.x = cc16[4 * u]; o.y = cc16[4 * u + 1];
            o.z = cc16[4 * u + 2]; o.w = cc16[4 * u + 3];
            *(float4*)&cpw[(r << 5) + c0 + (u << 2)] = o;
        }
    }
    __syncthreads();

    // ---- sum the 4 wave planes + bias -> cacc, then LN(1024) ----
    const int tt0 = tid << 2;
    float cacc0, cacc1, cacc2, cacc3;
    {
        const float* pl0 = (const float*)(sm_ + 32768);
        const float* pl1 = (const float*)(sm_ + 32768 + 4608);
        const float* pl2 = (const float*)(sm_ + 32768 + 9216);
        const float* pl3 = (const float*)(sm_ + 32768 + 13824);
        float4 q0 = *(const float4*)&pl0[tt0];
        float4 q1 = *(const float4*)&pl1[tt0];
        float4 q2 = *(const float4*)&pl2[tt0];
        float4 q3 = *(const float4*)&pl3[tt0];
        const float bb = tbias[0];
        cacc0 = q0.x + q1.x + q2.x + q3.x + bb;
        cacc1 = q0.y + q1.y + q2.y + q3.y + bb;
        cacc2 = q0.z + q1.z + q2.z + q3.z + bb;
        cacc3 = q0.w + q1.w + q2.w + q3.w + bb;
    }
    float mu, rs;
    {
        float s1 = cacc0 + cacc1 + cacc2 + cacc3;
        float s2 = cacc0 * cacc0 + cacc1 * cacc1 + cacc2 * cacc2 + cacc3 * cacc3;
        #pragma unroll
        for (int off = 32; off > 0; off >>= 1) {
            s1 += __shfl_down(s1, off);
            s2 += __shfl_down(s2, off);
        }
        if ((tid & 63) == 0) { redv[tid >> 6] = s1; redv[4 + (tid >> 6)] = s2; }
        __syncthreads();
        float t1 = redv[0] + redv[1] + redv[2] + redv[3];
        float t2 = redv[4] + redv[5] + redv[6] + redv[7];
        mu = t1 * (1.f / 1024.f);
        float var = t2 * (1.f / 1024.f) - mu * mu;
        rs = rsqrtf(var + 1e-5f);
    }
    float* nls = (float*)sm_;   // overlay region A (X planes dead now)
    {
        float4 g4 = *(const float4*)&lng[tt0];
        float4 b4 = *(const float4*)&lnb[tt0];
        float4 nv;
        nv.x = (cacc0 - mu) * rs * g4.x + b4.x;
        nv.y = (cacc1 - mu) * rs * g4.y + b4.y;
        nv.z = (cacc2 - mu) * rs * g4.z + b4.z;
        nv.w = (cacc3 - mu) * rs * g4.w + b4.w;
        *(float4*)&nls[tt0] = nv;
    }
    __syncthreads();
    // ---- MLP layer 1: 1024 -> 32 (split the dot over 8 thread-groups) ----
    {
        const int m = tid & 31;
        const int grp = tid >> 5;
        const int base = grp * 128;
        float p = 0.f;
        for (int u = 0; u < 128; ++u)
            p += nls[base + u] * w1[(base + u) * 32 + m];
        scratch[(m << 3) + grp] = p;
    }
    __syncthreads();
    if (tid < 32) {
        float z = b1[tid];
        #pragma unroll
        for (int g = 0; g < 8; ++g) z += scratch[(tid << 3) + g];
        z = 0.5f * z * (1.f + erff(z * 0.70710678118654752f));  // exact GELU
        h1s[tid] = z;
    }
    __syncthreads();
    // ---- MLP layer 2 + residual + store ----
    {
        float4 o4 = *(const float4*)&b2[tt0];
        #pragma unroll
        for (int m = 0; m < 32; ++m) {
            float hm = h1s[m];
            float4 w4 = *(const float4*)&w2[m * 1024 + tt0];
            o4.x += hm * w4.x; o4.y += hm * w4.y;
            o4.z += hm * w4.z; o4.w += hm * w4.w;
        }
        float4 res;
        res.x = cacc0 + o4.x; res.y = cacc1 + o4.y;
        res.z = cacc2 + o4.z; res.w = cacc3 + o4.w;
        float* outp = affbuf + (((size_t)(b * L_ + l)) << 10) + tt0;
        *(float4*)outp = res;
    }
}

// ---------------- Kernel B: p_conv (1024ch 3x3 -> 1), one wg per (b, pixel) --
__global__ __launch_bounds__(256)
void pconv_kernel(const float* __restrict__ affbuf, const float* __restrict__ pw,
                  const float* __restrict__ pb, float* __restrict__ yt)
{
    const int p = blockIdx.x;     // 0..195
    const int b = blockIdx.y;
    const int p1 = p / 14, p2 = p % 14;
    const int tid = threadIdx.x;
    __shared__ float pwS[9216];
    __shared__ float red4[4];
    for (int u = tid << 2; u < 9216; u += 1024)
        *(float4*)&pwS[u] = *(const float4*)&pw[u];
    __syncthreads();
    float acc = 0.f;
    #pragma unroll
    for (int di = 0; di < 3; ++di) {
        const int r = p1 + di - 1;
        if ((unsigned)r >= 14u) continue;
        #pragma unroll
        for (int dj = 0; dj < 3; ++dj) {
            const int c = p2 + dj - 1;
            if ((unsigned)c >= 14u) continue;
            const float* ap = affbuf + (((size_t)(b * 196 + r * 14 + c)) << 10);
            const int wo = di * 3 + dj;
            for (int u = tid; u < 1024; u += 256)
                acc += ap[u] * pwS[u * 9 + wo];
        }
    }
    #pragma unroll
    for (int off = 32; off > 0; off >>= 1) acc += __shfl_down(acc, off);
    if ((tid & 63) == 0) red4[tid >> 6] = acc;
    __syncthreads();
    if (tid == 0) yt[b * 196 + p] = red4[0] + red4[1] + red4[2] + red4[3] + pb[0];
}

// ---------------- Kernel C: spatial path, one wg per (b, t) -----------------
__global__ __launch_bounds__(256)
void spatial_kernel(const float* __restrict__ k, const float* __restrict__ v,
                    const float* __restrict__ syno, float* __restrict__ ys)
{
    const int t = blockIdx.x;   // 0..31
    const int b = blockIdx.y;   // 0..15
    const int tid = threadIdx.x;
    __shared__ float Ls[16 * 208];
    __shared__ float mxs[16], sms[16];
    __shared__ float ps[196];

    const size_t base = ((size_t)(b * T_ + t) * 197 + 1) * DM_;
    const float inv_sqrt_dm = 0.036084391824352f;  // 1/sqrt(768)

    if (tid < 196) {
        const float* kp = k + base + (size_t)tid * DM_;
        float acc[16];
        #pragma unroll
        for (int s = 0; s < 16; ++s) acc[s] = 0.f;
        for (int c0 = 0; c0 < DM_; c0 += 32) {
            float4 chunk[8];
            #pragma unroll
            for (int u = 0; u < 8; ++u) chunk[u] = *(const float4*)(kp + c0 + u * 4);
            #pragma unroll
            for (int s = 0; s < 16; ++s) {
                const float* sp = syno + s * DM_ + c0;   // uniform -> scalar loads
                float a = 0.f;
                #pragma unroll
                for (int u = 0; u < 8; ++u) {
                    a += chunk[u].x * sp[u * 4 + 0] + chunk[u].y * sp[u * 4 + 1]
                       + chunk[u].z * sp[u * 4 + 2] + chunk[u].w * sp[u * 4 + 3];
                }
                acc[s] += a;
            }
        }
        #pragma unroll
        for (int s = 0; s < 16; ++s) Ls[s * 208 + tid] = acc[s] * inv_sqrt_dm;
    }
    __syncthreads();
    {
        const int s = tid >> 4, j = tid & 15;
        float m = -1e30f;
        for (int l = j; l < 196; l += 16) m = fmaxf(m, Ls[s * 208 + l]);
        #pragma unroll
        for (int msk = 1; msk < 16; msk <<= 1) m = fmaxf(m, __shfl_xor(m, msk, 16));
        float sum = 0.f;
        for (int l = j; l < 196; l += 16) sum += __expf(Ls[s * 208 + l] - m);
        #pragma unroll
        for (int msk = 1; msk < 16; msk <<= 1) sum += __shfl_xor(sum, msk, 16);
        if (j == 0) { mxs[s] = m; sms[s] = 1.f / sum; }
    }
    __syncthreads();
    if (tid < 196) {
        float p = 0.f;
        #pragma unroll
        for (int s = 0; s < 16; ++s) p += __expf(Ls[s * 208 + tid] - mxs[s]) * sms[s];
        ps[tid] = p;
    }
    __syncthreads();
    if (tid < 192) {
        const float* vp = v + base + tid * 4;
        float4 acc = {0.f, 0.f, 0.f, 0.f};
        for (int l = 0; l < 196; ++l) {
            float p = ps[l];
            float4 vv = *(const float4*)(vp + (size_t)l * DM_);
            acc.x += p * vv.x; acc.y += p * vv.y;
            acc.z += p * vv.z; acc.w += p * vv.w;
        }
        const float f = 1.f / 512.f;   // mean over T*S
        float* o = ys + b * DM_ + tid * 4;
        atomicAdd(o + 0, acc.x * f);
        atomicAdd(o + 1, acc.y * f);
        atomicAdd(o + 2, acc.z * f);
        atomicAdd(o + 3, acc.w * f);
    }
}

extern "C" void kernel_launch(void* const* d_in, const int* in_sizes, int n_in,
                              void* d_out, int out_size, void* d_ws, size_t ws_size,
                              hipStream_t stream) {
    const float* q    = (const float*)d_in[0];
    const float* k    = (const float*)d_in[1];
    const float* v    = (const float*)d_in[2];
    const float* tw   = (const float*)d_in[3];
    const float* tb   = (const float*)d_in[4];
    const float* lng  = (const float*)d_in[5];
    const float* lnb  = (const float*)d_in[6];
    const float* w1   = (const float*)d_in[7];
    const float* b1   = (const float*)d_in[8];
    const float* w2   = (const float*)d_in[9];
    const float* b2   = (const float*)d_in[10];
    const float* pw   = (const float*)d_in[11];
    const float* pb   = (const float*)d_in[12];
    const float* syno = (const float*)d_in[13];

    float* out = (float*)d_out;             // [0,3136) = y_t ; [3136,15424) = y_s
    float* affbuf = (float*)d_ws;           // 16*196*1024 floats = 12.85 MB

    hipMemsetAsync(d_out, 0, (size_t)out_size * sizeof(float), stream);

    temporal_kernel<<<dim3(L_, 16), 256, 0, stream>>>(q, k, tw, tb, lng, lnb,
                                                      w1, b1, w2, b2, affbuf);
    pconv_kernel<<<dim3(L_, 16), 256, 0, stream>>>(affbuf, pw, pb, out);
    spatial_kernel<<<dim3(T_, 16), 256, 0, stream>>>(k, v, syno, out + 3136);
}